// Round 3
// baseline (387.679 us; speedup 1.0000x reference)
//
#include <hip/hip_runtime.h>
#include <math.h>

#define B 16
#define D 32
#define NH 8
#define NO 24
#define C 768
#define H 64
#define W 64
#define H1 512
#define H2 256
#define H3 117
#define NP (NH * NO)     // 192
#define KSPLIT 4         // l1 split-K slices

__device__ inline float4 f4add(float4 a, float4 b) {
  return make_float4(a.x + b.x, a.y + b.y, a.z + b.z, a.w + b.w);
}

// ---------------------------------------------------------------------------
// Kernel 1: ROI mean pooling. grid (512, 3), block 256 = 4 waves.
// Wave w handles rows ya+w, ya+w+4, ...; x-loop unrolled x4 with 4 independent
// accumulators for MLP. LDS reduce across the 4 waves.
// ---------------------------------------------------------------------------
__global__ __launch_bounds__(256) void roi_pool_k(
    const float* __restrict__ feat, const float* __restrict__ boxes,
    float* __restrict__ pooled) {
  int bd = blockIdx.x;
  int b = bd >> 5;
  const float* bx = boxes + (size_t)bd * 4;
  float cx = bx[0], cy = bx[1], bw = bx[2], bh = bx[3];
  // Replicate reference rounding exactly: fp32 mul by 896, then div by 14.
  int xa = (int)floorf(__fdiv_rn(__fmul_rn(cx - 0.5f * bw, 896.0f), 14.0f));
  int ya = (int)floorf(__fdiv_rn(__fmul_rn(cy - 0.5f * bh, 896.0f), 14.0f));
  int xb = (int)floorf(__fdiv_rn(__fmul_rn(cx + 0.5f * bw, 896.0f), 14.0f));
  int yb = (int)floorf(__fdiv_rn(__fmul_rn(cy + 0.5f * bh, 896.0f), 14.0f));
  xa = max(xa, 0); ya = max(ya, 0); xb = min(xb, W); yb = min(yb, H);

  int t = threadIdx.x;
  int wv = t >> 6;
  int lane = t & 63;
  int c0 = blockIdx.y * 256 + lane * 4;
  const float* fb = feat + (size_t)b * (H * W * C) + c0;

  float4 s0 = make_float4(0.f, 0.f, 0.f, 0.f);
  float4 s1 = s0, s2 = s0, s3 = s0;
  for (int y = ya + wv; y < yb; y += 4) {
    const float* fr = fb + (size_t)y * (W * C);
    int x = xa;
    for (; x + 3 < xb; x += 4) {
      float4 v0 = *(const float4*)(fr + (size_t)(x + 0) * C);
      float4 v1 = *(const float4*)(fr + (size_t)(x + 1) * C);
      float4 v2 = *(const float4*)(fr + (size_t)(x + 2) * C);
      float4 v3 = *(const float4*)(fr + (size_t)(x + 3) * C);
      s0 = f4add(s0, v0); s1 = f4add(s1, v1);
      s2 = f4add(s2, v2); s3 = f4add(s3, v3);
    }
    for (; x < xb; ++x)
      s0 = f4add(s0, *(const float4*)(fr + (size_t)x * C));
  }
  s0 = f4add(f4add(s0, s1), f4add(s2, s3));

  __shared__ float4 red[4][64];
  red[wv][lane] = s0;
  __syncthreads();
  if (wv == 0) {
    float4 a = f4add(f4add(red[0][lane], red[1][lane]),
                     f4add(red[2][lane], red[3][lane]));
    float area = (float)((yb - ya) * (xb - xa));
    float4 r;
    r.x = __fdiv_rn(a.x, area);
    r.y = __fdiv_rn(a.y, area);
    r.z = __fdiv_rn(a.z, area);
    r.w = __fdiv_rn(a.w, area);
    *(float4*)(pooled + (size_t)bd * C + c0) = r;
  }
}

// ---------------------------------------------------------------------------
// Kernel 2: layer-1 GEMM, native-layout weights (coalesced lane-stride 16B),
// A-tile broadcast from LDS, split-K x4.
// grid (64 row-tiles, 4 k-slices), block 128. Thread: 8 rows x 4 cols (4t..).
// Humans use w1 rows [0,768), objects [768,1536). Bias deferred to mlp_k.
// ---------------------------------------------------------------------------
__global__ __launch_bounds__(128) void l1_k(
    const float* __restrict__ pooled, const float* __restrict__ w1,
    float* __restrict__ php, float* __restrict__ pop) {
  __shared__ float a_lds[8 * 192];   // 6 KB
  int t = threadIdx.x;
  int tile = blockIdx.x;             // 0..63
  int kh = blockIdx.y;               // 0..3
  int rr0 = tile * 8;
  int b = rr0 >> 5;
  bool human = ((tile & 3) == 0);
  int kbase = kh * 192;

  // Stage A: 8 rows x 192 k-floats (coalesced float4 global reads).
  {
    const float* src = pooled + (size_t)rr0 * C + kbase;
    for (int idx = t; idx < 384; idx += 128) {
      int r = idx / 48, c = idx % 48;
      ((float4*)a_lds)[r * 48 + c] = *(const float4*)(src + (size_t)r * C + c * 4);
    }
  }
  __syncthreads();

  int kg0 = (human ? 0 : C) + kbase;
  const float* wp = w1 + (size_t)kg0 * H1 + 4 * t;   // lane-stride 16B

  float4 acc[8];
  #pragma unroll
  for (int r = 0; r < 8; ++r) acc[r] = make_float4(0.f, 0.f, 0.f, 0.f);

  for (int kk = 0; kk < 192; kk += 4) {
    float4 w0 = *(const float4*)(wp + (size_t)(kk + 0) * H1);
    float4 w1v = *(const float4*)(wp + (size_t)(kk + 1) * H1);
    float4 w2v = *(const float4*)(wp + (size_t)(kk + 2) * H1);
    float4 w3v = *(const float4*)(wp + (size_t)(kk + 3) * H1);
    #pragma unroll
    for (int r = 0; r < 8; ++r) {
      float4 a = *(const float4*)(a_lds + r * 192 + kk);  // LDS broadcast
      acc[r].x = fmaf(a.x, w0.x, acc[r].x);
      acc[r].y = fmaf(a.x, w0.y, acc[r].y);
      acc[r].z = fmaf(a.x, w0.z, acc[r].z);
      acc[r].w = fmaf(a.x, w0.w, acc[r].w);
      acc[r].x = fmaf(a.y, w1v.x, acc[r].x);
      acc[r].y = fmaf(a.y, w1v.y, acc[r].y);
      acc[r].z = fmaf(a.y, w1v.z, acc[r].z);
      acc[r].w = fmaf(a.y, w1v.w, acc[r].w);
      acc[r].x = fmaf(a.z, w2v.x, acc[r].x);
      acc[r].y = fmaf(a.z, w2v.y, acc[r].y);
      acc[r].z = fmaf(a.z, w2v.z, acc[r].z);
      acc[r].w = fmaf(a.z, w2v.w, acc[r].w);
      acc[r].x = fmaf(a.w, w3v.x, acc[r].x);
      acc[r].y = fmaf(a.w, w3v.y, acc[r].y);
      acc[r].z = fmaf(a.w, w3v.z, acc[r].z);
      acc[r].w = fmaf(a.w, w3v.w, acc[r].w);
    }
  }

  if (human) {
    #pragma unroll
    for (int r = 0; r < 8; ++r) {
      size_t row = ((size_t)kh * B + b) * NH + r;
      *(float4*)(php + row * H1 + 4 * t) = acc[r];
    }
  } else {
    int dbase = (tile & 3) * 8 - NH;
    #pragma unroll
    for (int r = 0; r < 8; ++r) {
      size_t row = ((size_t)kh * B + b) * NO + dbase + r;
      *(float4*)(pop + row * H1 + 4 * t) = acc[r];
    }
  }
}

// ---------------------------------------------------------------------------
// Kernel 3: fused sort + pair-build + L2 + L3.
// grid (B*24): block = (batch b, human-rank i, 8 object-ranks j0..j0+7).
// Per block: rank-sort 32 scores in-block; build x1 tile (8x512) in LDS
// (sum 4 k-slices + b1, relu); L2 into x2 LDS tile (8x256); L3 to out.
// All weight loads native-layout, coalesced. A always LDS-broadcast.
// ---------------------------------------------------------------------------
__global__ __launch_bounds__(128) void mlp_k(
    const float* __restrict__ php, const float* __restrict__ pop,
    const float* __restrict__ scores, const float* __restrict__ b1,
    const float* __restrict__ w2, const float* __restrict__ b2,
    const float* __restrict__ w3, const float* __restrict__ b3,
    float* __restrict__ out) {
  __shared__ float x1s[8 * H1];   // 16 KB
  __shared__ float x2s[8 * H2];   // 8 KB
  __shared__ int inv[D];          // rank -> index (humans [0,8), objects [8,32))
  int t = threadIdx.x;
  int blk = blockIdx.x;           // 0..383
  int b = blk / 24;
  int tile = blk % 24;
  int i = tile / 3;               // human rank
  int j0 = (tile % 3) * 8;        // first object rank

  // In-block stable descending rank-sort of the 32 scores.
  if (t < D) {
    const float* s = scores + (size_t)b * D;
    float v = s[t];
    if (t < NH) {
      int r = 0;
      for (int j = 0; j < NH; ++j) {
        float u = s[j];
        r += (u > v) || (u == v && j < t);
      }
      inv[r] = t;
    } else {
      int r = 0;
      for (int j = NH; j < D; ++j) {
        float u = s[j];
        r += (u > v) || (u == v && j < t);
      }
      inv[NH + r] = t - NH;
    }
  }
  __syncthreads();

  // Pair build: h segment (shared by all 8 rows) + per-row o segment.
  int hi = inv[i];
  float4 hs = make_float4(0.f, 0.f, 0.f, 0.f);
  #pragma unroll
  for (int s = 0; s < KSPLIT; ++s) {
    const float4* p = (const float4*)(php + (((size_t)s * B + b) * NH + hi) * H1);
    hs = f4add(hs, p[t]);
  }
  hs = f4add(hs, ((const float4*)b1)[t]);
  #pragma unroll
  for (int r = 0; r < 8; ++r) {
    int oj = inv[NH + j0 + r];
    float4 os = make_float4(0.f, 0.f, 0.f, 0.f);
    #pragma unroll
    for (int s = 0; s < KSPLIT; ++s) {
      const float4* p = (const float4*)(pop + (((size_t)s * B + b) * NO + oj) * H1);
      os = f4add(os, p[t]);
    }
    float4 x = f4add(hs, os);
    x.x = fmaxf(x.x, 0.f); x.y = fmaxf(x.y, 0.f);
    x.z = fmaxf(x.z, 0.f); x.w = fmaxf(x.w, 0.f);
    *(float4*)(x1s + r * H1 + 4 * t) = x;
  }
  __syncthreads();

  // L2: thread covers cols (2t, 2t+1); weights coalesced float2 (stride 8B).
  {
    float accA[8], accB[8];
    #pragma unroll
    for (int r = 0; r < 8; ++r) { accA[r] = 0.f; accB[r] = 0.f; }
    const float* wbase = w2 + 2 * t;
    for (int kc = 0; kc < H1; kc += 4) {
      float2 wk0 = *(const float2*)(wbase + (size_t)(kc + 0) * H2);
      float2 wk1 = *(const float2*)(wbase + (size_t)(kc + 1) * H2);
      float2 wk2 = *(const float2*)(wbase + (size_t)(kc + 2) * H2);
      float2 wk3 = *(const float2*)(wbase + (size_t)(kc + 3) * H2);
      #pragma unroll
      for (int r = 0; r < 8; ++r) {
        float4 a = *(const float4*)(x1s + r * H1 + kc);  // broadcast
        accA[r] = fmaf(a.x, wk0.x, accA[r]);
        accB[r] = fmaf(a.x, wk0.y, accB[r]);
        accA[r] = fmaf(a.y, wk1.x, accA[r]);
        accB[r] = fmaf(a.y, wk1.y, accB[r]);
        accA[r] = fmaf(a.z, wk2.x, accA[r]);
        accB[r] = fmaf(a.z, wk2.y, accB[r]);
        accA[r] = fmaf(a.w, wk3.x, accA[r]);
        accB[r] = fmaf(a.w, wk3.y, accB[r]);
      }
    }
    float bA = b2[2 * t], bB = b2[2 * t + 1];
    #pragma unroll
    for (int r = 0; r < 8; ++r) {
      float2 v;
      v.x = fmaxf(accA[r] + bA, 0.f);
      v.y = fmaxf(accB[r] + bB, 0.f);
      *(float2*)(x2s + r * H2 + 2 * t) = v;
    }
  }
  __syncthreads();

  // L3: thread covers col t (t<117); weights coalesced dword (stride 4B).
  if (t < H3) {
    float acc3[8];
    #pragma unroll
    for (int r = 0; r < 8; ++r) acc3[r] = 0.f;
    const float* wbase = w3 + t;
    for (int kc = 0; kc < H2; kc += 4) {
      float w0 = wbase[(size_t)(kc + 0) * H3];
      float w1v = wbase[(size_t)(kc + 1) * H3];
      float w2v = wbase[(size_t)(kc + 2) * H3];
      float w3v = wbase[(size_t)(kc + 3) * H3];
      #pragma unroll
      for (int r = 0; r < 8; ++r) {
        float4 a = *(const float4*)(x2s + r * H2 + kc);  // broadcast
        acc3[r] = fmaf(a.x, w0, acc3[r]);
        acc3[r] = fmaf(a.y, w1v, acc3[r]);
        acc3[r] = fmaf(a.z, w2v, acc3[r]);
        acc3[r] = fmaf(a.w, w3v, acc3[r]);
      }
    }
    float bias = b3[t];
    size_t g0 = (size_t)b * NP + (size_t)i * NO + j0;
    #pragma unroll
    for (int r = 0; r < 8; ++r)
      out[(g0 + r) * H3 + t] = acc3[r] + bias;
  }
}

// ---------------------------------------------------------------------------
extern "C" void kernel_launch(void* const* d_in, const int* in_sizes, int n_in,
                              void* d_out, int out_size, void* d_ws,
                              size_t ws_size, hipStream_t stream) {
  const float* feat   = (const float*)d_in[0];
  const float* boxes  = (const float*)d_in[1];
  const float* scores = (const float*)d_in[2];
  const float* w1     = (const float*)d_in[3];  // [1536,512]
  const float* b1     = (const float*)d_in[4];
  const float* w2     = (const float*)d_in[5];  // [512,256]
  const float* b2     = (const float*)d_in[6];
  const float* w3     = (const float*)d_in[7];  // [256,117]
  const float* b3     = (const float*)d_in[8];
  float* out = (float*)d_out;

  // Workspace (floats), ~5.8 MB total.
  float* base   = (float*)d_ws;
  float* pooled = base;                          // 16*32*768        = 393216
  float* php    = base + 393216;                 // 4*16*8*512       = 262144
  float* pop    = php + 262144;                  // 4*16*24*512      = 786432

  roi_pool_k<<<dim3(B * D, 3), 256, 0, stream>>>(feat, boxes, pooled);
  l1_k<<<dim3(64, KSPLIT), 128, 0, stream>>>(pooled, w1, php, pop);
  mlp_k<<<dim3(B * 24), 128, 0, stream>>>(php, pop, scores, b1, w2, b2, w3, b3,
                                          out);
}

// Round 4
// 366.375 us; speedup vs baseline: 1.0581x; 1.0581x over previous
//
#include <hip/hip_runtime.h>
#include <math.h>

#define B 16
#define D 32
#define NH 8
#define NO 24
#define C 768
#define H 64
#define W 64
#define H1 512
#define H2 256
#define H3 117
#define NP (NH * NO)     // 192
#define KSPLIT 4         // l1 split-K slices

__device__ inline float4 f4add(float4 a, float4 b) {
  return make_float4(a.x + b.x, a.y + b.y, a.z + b.z, a.w + b.w);
}

// ---------------------------------------------------------------------------
// Kernel 1: ROI mean pooling. grid (512, 3), block 256 = 4 waves.
// Near HBM-bound (~234 MB of feature reads): keep it simple.
// ---------------------------------------------------------------------------
__global__ __launch_bounds__(256) void roi_pool_k(
    const float* __restrict__ feat, const float* __restrict__ boxes,
    float* __restrict__ pooled) {
  int bd = blockIdx.x;
  int b = bd >> 5;
  const float* bx = boxes + (size_t)bd * 4;
  float cx = bx[0], cy = bx[1], bw = bx[2], bh = bx[3];
  // Replicate reference rounding exactly: fp32 mul by 896, then div by 14.
  int xa = (int)floorf(__fdiv_rn(__fmul_rn(cx - 0.5f * bw, 896.0f), 14.0f));
  int ya = (int)floorf(__fdiv_rn(__fmul_rn(cy - 0.5f * bh, 896.0f), 14.0f));
  int xb = (int)floorf(__fdiv_rn(__fmul_rn(cx + 0.5f * bw, 896.0f), 14.0f));
  int yb = (int)floorf(__fdiv_rn(__fmul_rn(cy + 0.5f * bh, 896.0f), 14.0f));
  xa = max(xa, 0); ya = max(ya, 0); xb = min(xb, W); yb = min(yb, H);

  int t = threadIdx.x;
  int wv = t >> 6;
  int lane = t & 63;
  int c0 = blockIdx.y * 256 + lane * 4;
  const float* fb = feat + (size_t)b * (H * W * C) + c0;

  float4 s0 = make_float4(0.f, 0.f, 0.f, 0.f);
  float4 s1 = s0, s2 = s0, s3 = s0;
  for (int y = ya + wv; y < yb; y += 4) {
    const float* fr = fb + (size_t)y * (W * C);
    int x = xa;
    for (; x + 3 < xb; x += 4) {
      float4 v0 = *(const float4*)(fr + (size_t)(x + 0) * C);
      float4 v1 = *(const float4*)(fr + (size_t)(x + 1) * C);
      float4 v2 = *(const float4*)(fr + (size_t)(x + 2) * C);
      float4 v3 = *(const float4*)(fr + (size_t)(x + 3) * C);
      s0 = f4add(s0, v0); s1 = f4add(s1, v1);
      s2 = f4add(s2, v2); s3 = f4add(s3, v3);
    }
    for (; x < xb; ++x)
      s0 = f4add(s0, *(const float4*)(fr + (size_t)x * C));
  }
  s0 = f4add(f4add(s0, s1), f4add(s2, s3));

  __shared__ float4 red[4][64];
  red[wv][lane] = s0;
  __syncthreads();
  if (wv == 0) {
    float4 a = f4add(f4add(red[0][lane], red[1][lane]),
                     f4add(red[2][lane], red[3][lane]));
    float area = (float)((yb - ya) * (xb - xa));
    float4 r;
    r.x = __fdiv_rn(a.x, area);
    r.y = __fdiv_rn(a.y, area);
    r.z = __fdiv_rn(a.z, area);
    r.w = __fdiv_rn(a.w, area);
    *(float4*)(pooled + (size_t)bd * c0 * 0 + (size_t)bd * C + c0) = r;
  }
}

// ---------------------------------------------------------------------------
// Kernel 2: layer-1 GEMM. 4-row tiles for occupancy: grid (128, 4) = 512
// blocks (~2/CU, 4 waves/CU). block 128; thread = 4 rows x 4 cols (float4 @4t).
// Weights native-layout (lane-stride 16B, coalesced). Bias deferred to mlp_k.
// tile: b = tile>>3, sub = tile&7; sub 0-1 = human 4-row groups, 2-7 = object.
// ---------------------------------------------------------------------------
__global__ __launch_bounds__(128) void l1_k(
    const float* __restrict__ pooled, const float* __restrict__ w1,
    float* __restrict__ php, float* __restrict__ pop) {
  __shared__ float a_lds[4 * 192];   // 3 KB
  int t = threadIdx.x;
  int tile = blockIdx.x;             // 0..127
  int kh = blockIdx.y;               // 0..3
  int b = tile >> 3;
  int sub = tile & 7;
  bool human = (sub < 2);
  int grp = human ? sub * 4 : 8 + (sub - 2) * 4;  // first row within image
  int rr0 = b * D + grp;
  int kbase = kh * 192;

  // Stage A: 4 rows x 192 k-floats (48 float4 per row).
  {
    const float* src = pooled + (size_t)rr0 * C + kbase;
    for (int idx = t; idx < 192; idx += 128) {
      int r = idx / 48, c = idx % 48;
      ((float4*)a_lds)[idx] = *(const float4*)(src + (size_t)r * C + c * 4);
    }
  }
  __syncthreads();

  int kg0 = (human ? 0 : C) + kbase;
  const float* wp = w1 + (size_t)kg0 * H1 + 4 * t;

  float4 acc[4];
  #pragma unroll
  for (int r = 0; r < 4; ++r) acc[r] = make_float4(0.f, 0.f, 0.f, 0.f);

  for (int kk = 0; kk < 192; kk += 4) {
    float4 w0 = *(const float4*)(wp + (size_t)(kk + 0) * H1);
    float4 w1v = *(const float4*)(wp + (size_t)(kk + 1) * H1);
    float4 w2v = *(const float4*)(wp + (size_t)(kk + 2) * H1);
    float4 w3v = *(const float4*)(wp + (size_t)(kk + 3) * H1);
    #pragma unroll
    for (int r = 0; r < 4; ++r) {
      float4 a = *(const float4*)(a_lds + r * 192 + kk);  // LDS broadcast
      acc[r].x = fmaf(a.x, w0.x, acc[r].x);
      acc[r].y = fmaf(a.x, w0.y, acc[r].y);
      acc[r].z = fmaf(a.x, w0.z, acc[r].z);
      acc[r].w = fmaf(a.x, w0.w, acc[r].w);
      acc[r].x = fmaf(a.y, w1v.x, acc[r].x);
      acc[r].y = fmaf(a.y, w1v.y, acc[r].y);
      acc[r].z = fmaf(a.y, w1v.z, acc[r].z);
      acc[r].w = fmaf(a.y, w1v.w, acc[r].w);
      acc[r].x = fmaf(a.z, w2v.x, acc[r].x);
      acc[r].y = fmaf(a.z, w2v.y, acc[r].y);
      acc[r].z = fmaf(a.z, w2v.z, acc[r].z);
      acc[r].w = fmaf(a.z, w2v.w, acc[r].w);
      acc[r].x = fmaf(a.w, w3v.x, acc[r].x);
      acc[r].y = fmaf(a.w, w3v.y, acc[r].y);
      acc[r].z = fmaf(a.w, w3v.z, acc[r].z);
      acc[r].w = fmaf(a.w, w3v.w, acc[r].w);
    }
  }

  if (human) {
    #pragma unroll
    for (int r = 0; r < 4; ++r) {
      size_t row = ((size_t)kh * B + b) * NH + sub * 4 + r;
      *(float4*)(php + row * H1 + 4 * t) = acc[r];
    }
  } else {
    #pragma unroll
    for (int r = 0; r < 4; ++r) {
      size_t row = ((size_t)kh * B + b) * NO + (sub - 2) * 4 + r;
      *(float4*)(pop + row * H1 + 4 * t) = acc[r];
    }
  }
}

// ---------------------------------------------------------------------------
// Kernel 3: fused sort + pair-build + L2 + L3. 4-row tiles for occupancy:
// grid (768) blocks (~3/CU, 6 waves/CU), block 128.
// Block = (batch b, human-rank i, 4 object-ranks j0..j0+3).
// ---------------------------------------------------------------------------
__global__ __launch_bounds__(128) void mlp_k(
    const float* __restrict__ php, const float* __restrict__ pop,
    const float* __restrict__ scores, const float* __restrict__ b1,
    const float* __restrict__ w2, const float* __restrict__ b2,
    const float* __restrict__ w3, const float* __restrict__ b3,
    float* __restrict__ out) {
  __shared__ float x1s[4 * H1];   // 8 KB
  __shared__ float x2s[4 * H2];   // 4 KB
  __shared__ int inv[D];
  int t = threadIdx.x;
  int blk = blockIdx.x;           // 0..767
  int b = blk / 48;
  int rem = blk % 48;
  int i = rem / 6;                // human rank
  int j0 = (rem % 6) * 4;         // first object rank

  // In-block stable descending rank-sort of the 32 scores.
  if (t < D) {
    const float* s = scores + (size_t)b * D;
    float v = s[t];
    if (t < NH) {
      int r = 0;
      for (int j = 0; j < NH; ++j) {
        float u = s[j];
        r += (u > v) || (u == v && j < t);
      }
      inv[r] = t;
    } else {
      int r = 0;
      for (int j = NH; j < D; ++j) {
        float u = s[j];
        r += (u > v) || (u == v && j < t);
      }
      inv[NH + r] = t - NH;
    }
  }
  __syncthreads();

  // Pair build: h segment (shared by all 4 rows) + per-row o segment.
  int hi = inv[i];
  float4 hs = make_float4(0.f, 0.f, 0.f, 0.f);
  #pragma unroll
  for (int s = 0; s < KSPLIT; ++s) {
    const float4* p = (const float4*)(php + (((size_t)s * B + b) * NH + hi) * H1);
    hs = f4add(hs, p[t]);
  }
  hs = f4add(hs, ((const float4*)b1)[t]);
  #pragma unroll
  for (int r = 0; r < 4; ++r) {
    int oj = inv[NH + j0 + r];
    float4 os = make_float4(0.f, 0.f, 0.f, 0.f);
    #pragma unroll
    for (int s = 0; s < KSPLIT; ++s) {
      const float4* p = (const float4*)(pop + (((size_t)s * B + b) * NO + oj) * H1);
      os = f4add(os, p[t]);
    }
    float4 x = f4add(hs, os);
    x.x = fmaxf(x.x, 0.f); x.y = fmaxf(x.y, 0.f);
    x.z = fmaxf(x.z, 0.f); x.w = fmaxf(x.w, 0.f);
    *(float4*)(x1s + r * H1 + 4 * t) = x;
  }
  __syncthreads();

  // L2: thread covers cols (2t, 2t+1); weights coalesced float2 (stride 8B).
  {
    float accA[4], accB[4];
    #pragma unroll
    for (int r = 0; r < 4; ++r) { accA[r] = 0.f; accB[r] = 0.f; }
    const float* wbase = w2 + 2 * t;
    for (int kc = 0; kc < H1; kc += 4) {
      float2 wk0 = *(const float2*)(wbase + (size_t)(kc + 0) * H2);
      float2 wk1 = *(const float2*)(wbase + (size_t)(kc + 1) * H2);
      float2 wk2 = *(const float2*)(wbase + (size_t)(kc + 2) * H2);
      float2 wk3 = *(const float2*)(wbase + (size_t)(kc + 3) * H2);
      #pragma unroll
      for (int r = 0; r < 4; ++r) {
        float4 a = *(const float4*)(x1s + r * H1 + kc);  // broadcast
        accA[r] = fmaf(a.x, wk0.x, accA[r]);
        accB[r] = fmaf(a.x, wk0.y, accB[r]);
        accA[r] = fmaf(a.y, wk1.x, accA[r]);
        accB[r] = fmaf(a.y, wk1.y, accB[r]);
        accA[r] = fmaf(a.z, wk2.x, accA[r]);
        accB[r] = fmaf(a.z, wk2.y, accB[r]);
        accA[r] = fmaf(a.w, wk3.x, accA[r]);
        accB[r] = fmaf(a.w, wk3.y, accB[r]);
      }
    }
    float bA = b2[2 * t], bB = b2[2 * t + 1];
    #pragma unroll
    for (int r = 0; r < 4; ++r) {
      float2 v;
      v.x = fmaxf(accA[r] + bA, 0.f);
      v.y = fmaxf(accB[r] + bB, 0.f);
      *(float2*)(x2s + r * H2 + 2 * t) = v;
    }
  }
  __syncthreads();

  // L3: thread covers col t (t<117); weights coalesced dword (stride 4B).
  if (t < H3) {
    float acc3[4];
    #pragma unroll
    for (int r = 0; r < 4; ++r) acc3[r] = 0.f;
    const float* wbase = w3 + t;
    for (int kc = 0; kc < H2; kc += 4) {
      float w0 = wbase[(size_t)(kc + 0) * H3];
      float w1v = wbase[(size_t)(kc + 1) * H3];
      float w2v = wbase[(size_t)(kc + 2) * H3];
      float w3v = wbase[(size_t)(kc + 3) * H3];
      #pragma unroll
      for (int r = 0; r < 4; ++r) {
        float4 a = *(const float4*)(x2s + r * H2 + kc);  // broadcast
        acc3[r] = fmaf(a.x, w0, acc3[r]);
        acc3[r] = fmaf(a.y, w1v, acc3[r]);
        acc3[r] = fmaf(a.z, w2v, acc3[r]);
        acc3[r] = fmaf(a.w, w3v, acc3[r]);
      }
    }
    float bias = b3[t];
    size_t g0 = (size_t)b * NP + (size_t)i * NO + j0;
    #pragma unroll
    for (int r = 0; r < 4; ++r)
      out[(g0 + r) * H3 + t] = acc3[r] + bias;
  }
}

// ---------------------------------------------------------------------------
extern "C" void kernel_launch(void* const* d_in, const int* in_sizes, int n_in,
                              void* d_out, int out_size, void* d_ws,
                              size_t ws_size, hipStream_t stream) {
  const float* feat   = (const float*)d_in[0];
  const float* boxes  = (const float*)d_in[1];
  const float* scores = (const float*)d_in[2];
  const float* w1     = (const float*)d_in[3];  // [1536,512]
  const float* b1     = (const float*)d_in[4];
  const float* w2     = (const float*)d_in[5];  // [512,256]
  const float* b2     = (const float*)d_in[6];
  const float* w3     = (const float*)d_in[7];  // [256,117]
  const float* b3     = (const float*)d_in[8];
  float* out = (float*)d_out;

  // Workspace (floats), ~5.8 MB total.
  float* base   = (float*)d_ws;
  float* pooled = base;                          // 16*32*768        = 393216
  float* php    = base + 393216;                 // 4*16*8*512       = 262144
  float* pop    = php + 262144;                  // 4*16*24*512      = 786432

  roi_pool_k<<<dim3(B * D, 3), 256, 0, stream>>>(feat, boxes, pooled);
  l1_k<<<dim3(128, KSPLIT), 128, 0, stream>>>(pooled, w1, php, pop);
  mlp_k<<<dim3(B * 48), 128, 0, stream>>>(php, pop, scores, b1, w2, b2, w3, b3,
                                          out);
}

// Round 5
// 360.294 us; speedup vs baseline: 1.0760x; 1.0169x over previous
//
#include <hip/hip_runtime.h>
#include <math.h>

#define B 16
#define D 32
#define NH 8
#define NO 24
#define C 768
#define H 64
#define W 64
#define H1 512
#define H2 256
#define H3 117
#define NP (NH * NO)     // 192
#define KSPLIT 4         // l1 split-K slices
#define MR 6             // mlp rows per block

__device__ inline float4 f4add(float4 a, float4 b) {
  return make_float4(a.x + b.x, a.y + b.y, a.z + b.z, a.w + b.w);
}
__device__ inline float2 f2add(float2 a, float2 b) {
  return make_float2(a.x + b.x, a.y + b.y);
}

// ---------------------------------------------------------------------------
// Kernel 1: ROI mean pooling. grid (512, 3), block 256 = 4 waves.
// Wave w handles rows ya+w, ya+w+4, ...; x-loop unrolled x4 with 4 independent
// accumulators for memory-level parallelism. LDS reduce across the 4 waves.
// ~107 MB HBM fetch (union of touched patches) + ~127 MB L3-served re-reads.
// ---------------------------------------------------------------------------
__global__ __launch_bounds__(256) void roi_pool_k(
    const float* __restrict__ feat, const float* __restrict__ boxes,
    float* __restrict__ pooled) {
  int bd = blockIdx.x;
  int b = bd >> 5;
  const float* bx = boxes + (size_t)bd * 4;
  float cx = bx[0], cy = bx[1], bw = bx[2], bh = bx[3];
  // Replicate reference rounding exactly: fp32 mul by 896, then div by 14.
  int xa = (int)floorf(__fdiv_rn(__fmul_rn(cx - 0.5f * bw, 896.0f), 14.0f));
  int ya = (int)floorf(__fdiv_rn(__fmul_rn(cy - 0.5f * bh, 896.0f), 14.0f));
  int xb = (int)floorf(__fdiv_rn(__fmul_rn(cx + 0.5f * bw, 896.0f), 14.0f));
  int yb = (int)floorf(__fdiv_rn(__fmul_rn(cy + 0.5f * bh, 896.0f), 14.0f));
  xa = max(xa, 0); ya = max(ya, 0); xb = min(xb, W); yb = min(yb, H);

  int t = threadIdx.x;
  int wv = t >> 6;
  int lane = t & 63;
  int c0 = blockIdx.y * 256 + lane * 4;
  const float* fb = feat + (size_t)b * (H * W * C) + c0;

  float4 s0 = make_float4(0.f, 0.f, 0.f, 0.f);
  float4 s1 = s0, s2 = s0, s3 = s0;
  for (int y = ya + wv; y < yb; y += 4) {
    const float* fr = fb + (size_t)y * (W * C);
    int x = xa;
    for (; x + 3 < xb; x += 4) {
      float4 v0 = *(const float4*)(fr + (size_t)(x + 0) * C);
      float4 v1 = *(const float4*)(fr + (size_t)(x + 1) * C);
      float4 v2 = *(const float4*)(fr + (size_t)(x + 2) * C);
      float4 v3 = *(const float4*)(fr + (size_t)(x + 3) * C);
      s0 = f4add(s0, v0); s1 = f4add(s1, v1);
      s2 = f4add(s2, v2); s3 = f4add(s3, v3);
    }
    for (; x < xb; ++x)
      s0 = f4add(s0, *(const float4*)(fr + (size_t)x * C));
  }
  s0 = f4add(f4add(s0, s1), f4add(s2, s3));

  __shared__ float4 red[4][64];
  red[wv][lane] = s0;
  __syncthreads();
  if (wv == 0) {
    float4 a = f4add(f4add(red[0][lane], red[1][lane]),
                     f4add(red[2][lane], red[3][lane]));
    float area = (float)((yb - ya) * (xb - xa));
    float4 r;
    r.x = __fdiv_rn(a.x, area);
    r.y = __fdiv_rn(a.y, area);
    r.z = __fdiv_rn(a.z, area);
    r.w = __fdiv_rn(a.w, area);
    *(float4*)(pooled + (size_t)bd * C + c0) = r;
  }
}

// ---------------------------------------------------------------------------
// Kernel 2: layer-1 GEMM. 4-row tiles: grid (128, 4) = 512 blocks (2/CU,
// 4 waves/CU). block 128; thread = 4 rows x 4 cols (float4 @4t).
// Weights native-layout (lane-stride 16B, coalesced). Bias deferred to mlp_k.
// ---------------------------------------------------------------------------
__global__ __launch_bounds__(128) void l1_k(
    const float* __restrict__ pooled, const float* __restrict__ w1,
    float* __restrict__ php, float* __restrict__ pop) {
  __shared__ float a_lds[4 * 192];   // 3 KB
  int t = threadIdx.x;
  int tile = blockIdx.x;             // 0..127
  int kh = blockIdx.y;               // 0..3
  int b = tile >> 3;
  int sub = tile & 7;
  bool human = (sub < 2);
  int grp = human ? sub * 4 : 8 + (sub - 2) * 4;
  int rr0 = b * D + grp;
  int kbase = kh * 192;

  {
    const float* src = pooled + (size_t)rr0 * C + kbase;
    for (int idx = t; idx < 192; idx += 128) {
      int r = idx / 48, c = idx % 48;
      ((float4*)a_lds)[idx] = *(const float4*)(src + (size_t)r * C + c * 4);
    }
  }
  __syncthreads();

  int kg0 = (human ? 0 : C) + kbase;
  const float* wp = w1 + (size_t)kg0 * H1 + 4 * t;

  float4 acc[4];
  #pragma unroll
  for (int r = 0; r < 4; ++r) acc[r] = make_float4(0.f, 0.f, 0.f, 0.f);

  for (int kk = 0; kk < 192; kk += 4) {
    float4 w0 = *(const float4*)(wp + (size_t)(kk + 0) * H1);
    float4 w1v = *(const float4*)(wp + (size_t)(kk + 1) * H1);
    float4 w2v = *(const float4*)(wp + (size_t)(kk + 2) * H1);
    float4 w3v = *(const float4*)(wp + (size_t)(kk + 3) * H1);
    #pragma unroll
    for (int r = 0; r < 4; ++r) {
      float4 a = *(const float4*)(a_lds + r * 192 + kk);  // LDS broadcast
      acc[r].x = fmaf(a.x, w0.x, acc[r].x);
      acc[r].y = fmaf(a.x, w0.y, acc[r].y);
      acc[r].z = fmaf(a.x, w0.z, acc[r].z);
      acc[r].w = fmaf(a.x, w0.w, acc[r].w);
      acc[r].x = fmaf(a.y, w1v.x, acc[r].x);
      acc[r].y = fmaf(a.y, w1v.y, acc[r].y);
      acc[r].z = fmaf(a.y, w1v.z, acc[r].z);
      acc[r].w = fmaf(a.y, w1v.w, acc[r].w);
      acc[r].x = fmaf(a.z, w2v.x, acc[r].x);
      acc[r].y = fmaf(a.z, w2v.y, acc[r].y);
      acc[r].z = fmaf(a.z, w2v.z, acc[r].z);
      acc[r].w = fmaf(a.z, w2v.w, acc[r].w);
      acc[r].x = fmaf(a.w, w3v.x, acc[r].x);
      acc[r].y = fmaf(a.w, w3v.y, acc[r].y);
      acc[r].z = fmaf(a.w, w3v.z, acc[r].z);
      acc[r].w = fmaf(a.w, w3v.w, acc[r].w);
    }
  }

  if (human) {
    #pragma unroll
    for (int r = 0; r < 4; ++r) {
      size_t row = ((size_t)kh * B + b) * NH + sub * 4 + r;
      *(float4*)(php + row * H1 + 4 * t) = acc[r];
    }
  } else {
    #pragma unroll
    for (int r = 0; r < 4; ++r) {
      size_t row = ((size_t)kh * B + b) * NO + (sub - 2) * 4 + r;
      *(float4*)(pop + row * H1 + 4 * t) = acc[r];
    }
  }
}

// ---------------------------------------------------------------------------
// Kernel 3: fused sort + pair-build + L2 + L3.
// 6-row tiles, 256 threads: grid (512) = exactly 2 blocks/CU (balanced),
// 8 waves/CU. w2 L2-traffic 262 MB (vs 393 MB at 4-row tiles).
// Block = (batch b, human-rank i, 6 object-ranks j0..j0+5).
// L3 layer: two 128-thread halves each cover 3 rows x 117 cols.
// ---------------------------------------------------------------------------
__global__ __launch_bounds__(256) void mlp_k(
    const float* __restrict__ php, const float* __restrict__ pop,
    const float* __restrict__ scores, const float* __restrict__ b1,
    const float* __restrict__ w2, const float* __restrict__ b2,
    const float* __restrict__ w3, const float* __restrict__ b3,
    float* __restrict__ out) {
  __shared__ float x1s[MR * H1];   // 12 KB
  __shared__ float x2s[MR * H2];   // 6 KB
  __shared__ int inv[D];
  int t = threadIdx.x;             // 0..255
  int blk = blockIdx.x;            // 0..511
  int b = blk >> 5;
  int rem = blk & 31;
  int i = rem >> 2;                // human rank 0..7
  int j0 = (rem & 3) * MR;         // first object rank: 0,6,12,18

  // In-block stable descending rank-sort of the 32 scores.
  if (t < D) {
    const float* s = scores + (size_t)b * D;
    float v = s[t];
    if (t < NH) {
      int r = 0;
      for (int j = 0; j < NH; ++j) {
        float u = s[j];
        r += (u > v) || (u == v && j < t);
      }
      inv[r] = t;
    } else {
      int r = 0;
      for (int j = NH; j < D; ++j) {
        float u = s[j];
        r += (u > v) || (u == v && j < t);
      }
      inv[NH + r] = t - NH;
    }
  }
  __syncthreads();

  // Pair build: thread t covers cols (2t, 2t+1) as float2 (coalesced).
  int hi = inv[i];
  float2 hs = make_float2(0.f, 0.f);
  #pragma unroll
  for (int s = 0; s < KSPLIT; ++s) {
    const float2* p =
        (const float2*)(php + (((size_t)s * B + b) * NH + hi) * H1);
    hs = f2add(hs, p[t]);
  }
  hs = f2add(hs, ((const float2*)b1)[t]);
  #pragma unroll
  for (int r = 0; r < MR; ++r) {
    int oj = inv[NH + j0 + r];
    float2 os = make_float2(0.f, 0.f);
    #pragma unroll
    for (int s = 0; s < KSPLIT; ++s) {
      const float2* p =
          (const float2*)(pop + (((size_t)s * B + b) * NO + oj) * H1);
      os = f2add(os, p[t]);
    }
    float2 x = f2add(hs, os);
    x.x = fmaxf(x.x, 0.f);
    x.y = fmaxf(x.y, 0.f);
    *(float2*)(x1s + r * H1 + 2 * t) = x;
  }
  __syncthreads();

  // L2: thread covers col t (scalar w2 loads, lane-stride 4B, coalesced).
  {
    float acc[MR];
    #pragma unroll
    for (int r = 0; r < MR; ++r) acc[r] = 0.f;
    const float* wbase = w2 + t;
    for (int kc = 0; kc < H1; kc += 4) {
      float w0 = wbase[(size_t)(kc + 0) * H2];
      float w1v = wbase[(size_t)(kc + 1) * H2];
      float w2v = wbase[(size_t)(kc + 2) * H2];
      float w3v = wbase[(size_t)(kc + 3) * H2];
      #pragma unroll
      for (int r = 0; r < MR; ++r) {
        float4 a = *(const float4*)(x1s + r * H1 + kc);  // broadcast
        acc[r] = fmaf(a.x, w0, acc[r]);
        acc[r] = fmaf(a.y, w1v, acc[r]);
        acc[r] = fmaf(a.z, w2v, acc[r]);
        acc[r] = fmaf(a.w, w3v, acc[r]);
      }
    }
    float bias = b2[t];
    #pragma unroll
    for (int r = 0; r < MR; ++r)
      x2s[r * H2 + t] = fmaxf(acc[r] + bias, 0.f);
  }
  __syncthreads();

  // L3: half h = t>>7 covers rows h*3..h*3+2; col tt = t&127 (<117).
  {
    int h = t >> 7;
    int tt = t & 127;
    if (tt < H3) {
      float acc3[3];
      #pragma unroll
      for (int r = 0; r < 3; ++r) acc3[r] = 0.f;
      const float* wbase = w3 + tt;
      for (int kc = 0; kc < H2; kc += 4) {
        float w0 = wbase[(size_t)(kc + 0) * H3];
        float w1v = wbase[(size_t)(kc + 1) * H3];
        float w2v = wbase[(size_t)(kc + 2) * H3];
        float w3v = wbase[(size_t)(kc + 3) * H3];
        #pragma unroll
        for (int r = 0; r < 3; ++r) {
          float4 a = *(const float4*)(x2s + (h * 3 + r) * H2 + kc);
          acc3[r] = fmaf(a.x, w0, acc3[r]);
          acc3[r] = fmaf(a.y, w1v, acc3[r]);
          acc3[r] = fmaf(a.z, w2v, acc3[r]);
          acc3[r] = fmaf(a.w, w3v, acc3[r]);
        }
      }
      float bias = b3[tt];
      size_t g0 = (size_t)b * NP + (size_t)i * NO + j0 + h * 3;
      #pragma unroll
      for (int r = 0; r < 3; ++r)
        out[(g0 + r) * H3 + tt] = acc3[r] + bias;
    }
  }
}

// ---------------------------------------------------------------------------
extern "C" void kernel_launch(void* const* d_in, const int* in_sizes, int n_in,
                              void* d_out, int out_size, void* d_ws,
                              size_t ws_size, hipStream_t stream) {
  const float* feat   = (const float*)d_in[0];
  const float* boxes  = (const float*)d_in[1];
  const float* scores = (const float*)d_in[2];
  const float* w1     = (const float*)d_in[3];  // [1536,512]
  const float* b1     = (const float*)d_in[4];
  const float* w2     = (const float*)d_in[5];  // [512,256]
  const float* b2     = (const float*)d_in[6];
  const float* w3     = (const float*)d_in[7];  // [256,117]
  const float* b3     = (const float*)d_in[8];
  float* out = (float*)d_out;

  // Workspace (floats), ~5.8 MB total.
  float* base   = (float*)d_ws;
  float* pooled = base;                          // 16*32*768        = 393216
  float* php    = base + 393216;                 // 4*16*8*512       = 262144
  float* pop    = php + 262144;                  // 4*16*24*512     = 786432

  roi_pool_k<<<dim3(B * D, 3), 256, 0, stream>>>(feat, boxes, pooled);
  l1_k<<<dim3(128, KSPLIT), 128, 0, stream>>>(pooled, w1, php, pop);
  mlp_k<<<dim3(512), 256, 0, stream>>>(php, pop, scores, b1, w2, b2, w3, b3,
                                       out);
}

// Round 6
// 358.893 us; speedup vs baseline: 1.0802x; 1.0039x over previous
//
#include <hip/hip_runtime.h>
#include <math.h>

#define B 16
#define D 32
#define NH 8
#define NO 24
#define C 768
#define H 64
#define W 64
#define H1 512
#define H2 256
#define H3 117
#define NP (NH * NO)     // 192
#define KSPLIT 4         // l1 split-K slices
#define MR 6             // mlp rows per block

__device__ inline float4 f4add(float4 a, float4 b) {
  return make_float4(a.x + b.x, a.y + b.y, a.z + b.z, a.w + b.w);
}
__device__ inline float2 f2add(float2 a, float2 b) {
  return make_float2(a.x + b.x, a.y + b.y);
}

// ---------------------------------------------------------------------------
// Kernel 1: ROI mean pooling. grid (512, 3), block 256 = 4 waves.
// Wave w handles rows ya+w, ya+w+4, ...; x-loop unrolled x8 with 8 independent
// accumulators (avg box width ~12 -> one 8-chunk + remainder) to keep 8 loads
// in flight per wave. LDS reduce across the 4 waves.
// ~107 MB HBM fetch (union of touched patches); floor ~17 us at 6.3 TB/s.
// ---------------------------------------------------------------------------
__global__ __launch_bounds__(256) void roi_pool_k(
    const float* __restrict__ feat, const float* __restrict__ boxes,
    float* __restrict__ pooled) {
  int bd = blockIdx.x;
  int b = bd >> 5;
  const float* bx = boxes + (size_t)bd * 4;
  float cx = bx[0], cy = bx[1], bw = bx[2], bh = bx[3];
  // Replicate reference rounding exactly: fp32 mul by 896, then div by 14.
  int xa = (int)floorf(__fdiv_rn(__fmul_rn(cx - 0.5f * bw, 896.0f), 14.0f));
  int ya = (int)floorf(__fdiv_rn(__fmul_rn(cy - 0.5f * bh, 896.0f), 14.0f));
  int xb = (int)floorf(__fdiv_rn(__fmul_rn(cx + 0.5f * bw, 896.0f), 14.0f));
  int yb = (int)floorf(__fdiv_rn(__fmul_rn(cy + 0.5f * bh, 896.0f), 14.0f));
  xa = max(xa, 0); ya = max(ya, 0); xb = min(xb, W); yb = min(yb, H);

  int t = threadIdx.x;
  int wv = t >> 6;
  int lane = t & 63;
  int c0 = blockIdx.y * 256 + lane * 4;
  const float* fb = feat + (size_t)b * (H * W * C) + c0;

  float4 s0 = make_float4(0.f, 0.f, 0.f, 0.f);
  float4 s1 = s0, s2 = s0, s3 = s0, s4 = s0, s5 = s0, s6 = s0, s7 = s0;
  for (int y = ya + wv; y < yb; y += 4) {
    const float* fr = fb + (size_t)y * (W * C);
    int x = xa;
    for (; x + 7 < xb; x += 8) {
      float4 v0 = *(const float4*)(fr + (size_t)(x + 0) * C);
      float4 v1 = *(const float4*)(fr + (size_t)(x + 1) * C);
      float4 v2 = *(const float4*)(fr + (size_t)(x + 2) * C);
      float4 v3 = *(const float4*)(fr + (size_t)(x + 3) * C);
      float4 v4 = *(const float4*)(fr + (size_t)(x + 4) * C);
      float4 v5 = *(const float4*)(fr + (size_t)(x + 5) * C);
      float4 v6 = *(const float4*)(fr + (size_t)(x + 6) * C);
      float4 v7 = *(const float4*)(fr + (size_t)(x + 7) * C);
      s0 = f4add(s0, v0); s1 = f4add(s1, v1);
      s2 = f4add(s2, v2); s3 = f4add(s3, v3);
      s4 = f4add(s4, v4); s5 = f4add(s5, v5);
      s6 = f4add(s6, v6); s7 = f4add(s7, v7);
    }
    if (x + 3 < xb) {
      float4 v0 = *(const float4*)(fr + (size_t)(x + 0) * C);
      float4 v1 = *(const float4*)(fr + (size_t)(x + 1) * C);
      float4 v2 = *(const float4*)(fr + (size_t)(x + 2) * C);
      float4 v3 = *(const float4*)(fr + (size_t)(x + 3) * C);
      s0 = f4add(s0, v0); s1 = f4add(s1, v1);
      s2 = f4add(s2, v2); s3 = f4add(s3, v3);
      x += 4;
    }
    for (; x < xb; ++x)
      s0 = f4add(s0, *(const float4*)(fr + (size_t)x * C));
  }
  s0 = f4add(f4add(f4add(s0, s1), f4add(s2, s3)),
             f4add(f4add(s4, s5), f4add(s6, s7)));

  __shared__ float4 red[4][64];
  red[wv][lane] = s0;
  __syncthreads();
  if (wv == 0) {
    float4 a = f4add(f4add(red[0][lane], red[1][lane]),
                     f4add(red[2][lane], red[3][lane]));
    float area = (float)((yb - ya) * (xb - xa));
    float4 r;
    r.x = __fdiv_rn(a.x, area);
    r.y = __fdiv_rn(a.y, area);
    r.z = __fdiv_rn(a.z, area);
    r.w = __fdiv_rn(a.w, area);
    *(float4*)(pooled + (size_t)bd * C + c0) = r;
  }
}

// ---------------------------------------------------------------------------
// Kernel 2: layer-1 GEMM. 4-row tiles: grid (128, 4) = 512 blocks (2/CU,
// 4 waves/CU). block 128; thread = 4 rows x 4 cols (float4 @4t).
// Weights native-layout (lane-stride 16B, coalesced). Bias deferred to mlp_k.
// ---------------------------------------------------------------------------
__global__ __launch_bounds__(128) void l1_k(
    const float* __restrict__ pooled, const float* __restrict__ w1,
    float* __restrict__ php, float* __restrict__ pop) {
  __shared__ float a_lds[4 * 192];   // 3 KB
  int t = threadIdx.x;
  int tile = blockIdx.x;             // 0..127
  int kh = blockIdx.y;               // 0..3
  int b = tile >> 3;
  int sub = tile & 7;
  bool human = (sub < 2);
  int grp = human ? sub * 4 : 8 + (sub - 2) * 4;
  int rr0 = b * D + grp;
  int kbase = kh * 192;

  {
    const float* src = pooled + (size_t)rr0 * C + kbase;
    for (int idx = t; idx < 192; idx += 128) {
      int r = idx / 48, c = idx % 48;
      ((float4*)a_lds)[idx] = *(const float4*)(src + (size_t)r * C + c * 4);
    }
  }
  __syncthreads();

  int kg0 = (human ? 0 : C) + kbase;
  const float* wp = w1 + (size_t)kg0 * H1 + 4 * t;

  float4 acc[4];
  #pragma unroll
  for (int r = 0; r < 4; ++r) acc[r] = make_float4(0.f, 0.f, 0.f, 0.f);

  for (int kk = 0; kk < 192; kk += 4) {
    float4 w0 = *(const float4*)(wp + (size_t)(kk + 0) * H1);
    float4 w1v = *(const float4*)(wp + (size_t)(kk + 1) * H1);
    float4 w2v = *(const float4*)(wp + (size_t)(kk + 2) * H1);
    float4 w3v = *(const float4*)(wp + (size_t)(kk + 3) * H1);
    #pragma unroll
    for (int r = 0; r < 4; ++r) {
      float4 a = *(const float4*)(a_lds + r * 192 + kk);  // LDS broadcast
      acc[r].x = fmaf(a.x, w0.x, acc[r].x);
      acc[r].y = fmaf(a.x, w0.y, acc[r].y);
      acc[r].z = fmaf(a.x, w0.z, acc[r].z);
      acc[r].w = fmaf(a.x, w0.w, acc[r].w);
      acc[r].x = fmaf(a.y, w1v.x, acc[r].x);
      acc[r].y = fmaf(a.y, w1v.y, acc[r].y);
      acc[r].z = fmaf(a.y, w1v.z, acc[r].z);
      acc[r].w = fmaf(a.y, w1v.w, acc[r].w);
      acc[r].x = fmaf(a.z, w2v.x, acc[r].x);
      acc[r].y = fmaf(a.z, w2v.y, acc[r].y);
      acc[r].z = fmaf(a.z, w2v.z, acc[r].z);
      acc[r].w = fmaf(a.z, w2v.w, acc[r].w);
      acc[r].x = fmaf(a.w, w3v.x, acc[r].x);
      acc[r].y = fmaf(a.w, w3v.y, acc[r].y);
      acc[r].z = fmaf(a.w, w3v.z, acc[r].z);
      acc[r].w = fmaf(a.w, w3v.w, acc[r].w);
    }
  }

  if (human) {
    #pragma unroll
    for (int r = 0; r < 4; ++r) {
      size_t row = ((size_t)kh * B + b) * NH + sub * 4 + r;
      *(float4*)(php + row * H1 + 4 * t) = acc[r];
    }
  } else {
    #pragma unroll
    for (int r = 0; r < 4; ++r) {
      size_t row = ((size_t)kh * B + b) * NO + (sub - 2) * 4 + r;
      *(float4*)(pop + row * H1 + 4 * t) = acc[r];
    }
  }
}

// ---------------------------------------------------------------------------
// Kernel 3: fused sort + pair-build + L2 + L3.
// 6-row tiles, 256 threads: grid (512) = exactly 2 blocks/CU, 8 waves/CU.
// Block = (batch b, human-rank i, 6 object-ranks j0..j0+5).
// L3 layer: two 128-thread halves each cover 3 rows x 117 cols.
// ---------------------------------------------------------------------------
__global__ __launch_bounds__(256) void mlp_k(
    const float* __restrict__ php, const float* __restrict__ pop,
    const float* __restrict__ scores, const float* __restrict__ b1,
    const float* __restrict__ w2, const float* __restrict__ b2,
    const float* __restrict__ w3, const float* __restrict__ b3,
    float* __restrict__ out) {
  __shared__ float x1s[MR * H1];   // 12 KB
  __shared__ float x2s[MR * H2];   // 6 KB
  __shared__ int inv[D];
  int t = threadIdx.x;             // 0..255
  int blk = blockIdx.x;            // 0..511
  int b = blk >> 5;
  int rem = blk & 31;
  int i = rem >> 2;                // human rank 0..7
  int j0 = (rem & 3) * MR;         // first object rank: 0,6,12,18

  // In-block stable descending rank-sort of the 32 scores.
  if (t < D) {
    const float* s = scores + (size_t)b * D;
    float v = s[t];
    if (t < NH) {
      int r = 0;
      for (int j = 0; j < NH; ++j) {
        float u = s[j];
        r += (u > v) || (u == v && j < t);
      }
      inv[r] = t;
    } else {
      int r = 0;
      for (int j = NH; j < D; ++j) {
        float u = s[j];
        r += (u > v) || (u == v && j < t);
      }
      inv[NH + r] = t - NH;
    }
  }
  __syncthreads();

  // Pair build: thread t covers cols (2t, 2t+1) as float2 (coalesced).
  int hi = inv[i];
  float2 hs = make_float2(0.f, 0.f);
  #pragma unroll
  for (int s = 0; s < KSPLIT; ++s) {
    const float2* p =
        (const float2*)(php + (((size_t)s * B + b) * NH + hi) * H1);
    hs = f2add(hs, p[t]);
  }
  hs = f2add(hs, ((const float2*)b1)[t]);
  #pragma unroll
  for (int r = 0; r < MR; ++r) {
    int oj = inv[NH + j0 + r];
    float2 os = make_float2(0.f, 0.f);
    #pragma unroll
    for (int s = 0; s < KSPLIT; ++s) {
      const float2* p =
          (const float2*)(pop + (((size_t)s * B + b) * NO + oj) * H1);
      os = f2add(os, p[t]);
    }
    float2 x = f2add(hs, os);
    x.x = fmaxf(x.x, 0.f);
    x.y = fmaxf(x.y, 0.f);
    *(float2*)(x1s + r * H1 + 2 * t) = x;
  }
  __syncthreads();

  // L2: thread covers col t (scalar w2 loads, lane-stride 4B, coalesced).
  {
    float acc[MR];
    #pragma unroll
    for (int r = 0; r < MR; ++r) acc[r] = 0.f;
    const float* wbase = w2 + t;
    for (int kc = 0; kc < H1; kc += 4) {
      float w0 = wbase[(size_t)(kc + 0) * H2];
      float w1v = wbase[(size_t)(kc + 1) * H2];
      float w2v = wbase[(size_t)(kc + 2) * H2];
      float w3v = wbase[(size_t)(kc + 3) * H2];
      #pragma unroll
      for (int r = 0; r < MR; ++r) {
        float4 a = *(const float4*)(x1s + r * H1 + kc);  // broadcast
        acc[r] = fmaf(a.x, w0, acc[r]);
        acc[r] = fmaf(a.y, w1v, acc[r]);
        acc[r] = fmaf(a.z, w2v, acc[r]);
        acc[r] = fmaf(a.w, w3v, acc[r]);
      }
    }
    float bias = b2[t];
    #pragma unroll
    for (int r = 0; r < MR; ++r)
      x2s[r * H2 + t] = fmaxf(acc[r] + bias, 0.f);
  }
  __syncthreads();

  // L3: half h = t>>7 covers rows h*3..h*3+2; col tt = t&127 (<117).
  {
    int h = t >> 7;
    int tt = t & 127;
    if (tt < H3) {
      float acc3[3];
      #pragma unroll
      for (int r = 0; r < 3; ++r) acc3[r] = 0.f;
      const float* wbase = w3 + tt;
      for (int kc = 0; kc < H2; kc += 4) {
        float w0 = wbase[(size_t)(kc + 0) * H3];
        float w1v = wbase[(size_t)(kc + 1) * H3];
        float w2v = wbase[(size_t)(kc + 2) * H3];
        float w3v = wbase[(size_t)(kc + 3) * H3];
        #pragma unroll
        for (int r = 0; r < 3; ++r) {
          float4 a = *(const float4*)(x2s + (h * 3 + r) * H2 + kc);
          acc3[r] = fmaf(a.x, w0, acc3[r]);
          acc3[r] = fmaf(a.y, w1v, acc3[r]);
          acc3[r] = fmaf(a.z, w2v, acc3[r]);
          acc3[r] = fmaf(a.w, w3v, acc3[r]);
        }
      }
      float bias = b3[tt];
      size_t g0 = (size_t)b * NP + (size_t)i * NO + j0 + h * 3;
      #pragma unroll
      for (int r = 0; r < 3; ++r)
        out[(g0 + r) * H3 + tt] = acc3[r] + bias;
    }
  }
}

// ---------------------------------------------------------------------------
extern "C" void kernel_launch(void* const* d_in, const int* in_sizes, int n_in,
                              void* d_out, int out_size, void* d_ws,
                              size_t ws_size, hipStream_t stream) {
  const float* feat   = (const float*)d_in[0];
  const float* boxes  = (const float*)d_in[1];
  const float* scores = (const float*)d_in[2];
  const float* w1     = (const float*)d_in[3];  // [1536,512]
  const float* b1     = (const float*)d_in[4];
  const float* w2     = (const float*)d_in[5];  // [512,256]
  const float* b2     = (const float*)d_in[6];
  const float* w3     = (const float*)d_in[7];  // [256,117]
  const float* b3     = (const float*)d_in[8];
  float* out = (float*)d_out;

  // Workspace (floats), ~5.8 MB total.
  float* base   = (float*)d_ws;
  float* pooled = base;                          // 16*32*768        = 393216
  float* php    = base + 393216;                 // 4*16*8*512       = 262144
  float* pop    = php + 262144;                  // 4*16*24*512     = 786432

  roi_pool_k<<<dim3(B * D, 3), 256, 0, stream>>>(feat, boxes, pooled);
  l1_k<<<dim3(128, KSPLIT), 128, 0, stream>>>(pooled, w1, php, pop);
  mlp_k<<<dim3(512), 256, 0, stream>>>(php, pop, scores, b1, w2, b2, w3, b3,
                                       out);
}